// Round 8
// baseline (460.747 us; speedup 1.0000x reference)
//
#include <hip/hip_runtime.h>

#define VOCAB 27
#define EMB   32
#define HID   64
#define BATCH 4096
#define TLEN  256
#define WPB   4     // waves (batch rows) per block

// tanh(x) = 1 - 2/(exp2(2*log2e*x) + 1)   -- inline VALU, no libcall.
__device__ __forceinline__ float fast_tanh(float x) {
    float t = __builtin_amdgcn_exp2f(x * 2.885390081777927f); // 2/ln2
    float r = __builtin_amdgcn_rcpf(t + 1.0f);
    return fmaf(-2.0f, r, 1.0f);
}

__device__ __forceinline__ void fma4(float& acc, const float4& a, const float4& b) {
    acc = fmaf(a.x, b.x, acc);
    acc = fmaf(a.y, b.y, acc);
    acc = fmaf(a.z, b.z, acc);
    acc = fmaf(a.w, b.w, acc);
}

// Opaque identity: after this, the value cannot be rematerialized from its
// originating load — forces the allocator to keep it live in a VGPR.
__device__ __forceinline__ void pin4(float4& v) {
    asm volatile("" : "+v"(v.x), "+v"(v.y), "+v"(v.z), "+v"(v.w));
}

__global__ __launch_bounds__(256)
__attribute__((amdgpu_waves_per_eu(2, 3)))   // budget 256 regs; no occupancy-chasing
void rnn_fused(
    const int*   __restrict__ X,      // (B,T)
    const float* __restrict__ emb_w,  // (27,32)
    const float* __restrict__ start,  // (1,64)
    const float* __restrict__ rnn_w,  // (64,96)  [:, :32]=Wx  [:, 32:]=Wh
    const float* __restrict__ rnn_b,  // (64)
    const float* __restrict__ lm_w,   // (27,64)
    const float* __restrict__ lm_b,   // (27)
    float*       __restrict__ out)    // (B,T,27)
{
    __shared__ float table[VOCAB][HID];   // xp lookup: rnn_b + Wx . emb_w[v]
    __shared__ float hbuf[WPB][HID];      // per-wave h_{t-1} broadcast buffer
    __shared__ int   xrow[WPB][TLEN];     // per-wave token row

    const int tid  = threadIdx.x;
    const int lane = tid & 63;
    const int wave = tid >> 6;
    const int b    = blockIdx.x * WPB + wave;

    // Build the 27x64 xproj table once per block.
    for (int f = tid; f < VOCAB * HID; f += 256) {
        const int v = f >> 6, i = f & 63;
        float s = rnn_b[i];
        #pragma unroll
        for (int e = 0; e < EMB; ++e)
            s += rnn_w[i * (EMB + HID) + e] * emb_w[v * EMB + e];
        table[v][i] = s;
    }
    {
        const int* Xb = X + (size_t)b * TLEN;
        #pragma unroll
        for (int k = 0; k < TLEN / 64; ++k)
            xrow[wave][k * 64 + lane] = Xb[k * 64 + lane];
    }
    __syncthreads();

    // Wh row `lane`: 64 VGPRs, pinned resident (R6: allocator remat'd these
    // into per-step L1 reloads -> 40% VALU stall; VGPR_Count 92).
    float4 wh[16];
    #pragma unroll
    for (int k = 0; k < 16; ++k) {
        wh[k] = *(const float4*)&rnn_w[lane * (EMB + HID) + EMB + 4 * k];
        pin4(wh[k]);
    }

    // Logits half-split: half 0 sums j<32, half 1 sums j>=32 (32 VGPRs, pinned).
    const int vmod = lane & 31;
    const int vv   = vmod < VOCAB ? vmod : VOCAB - 1;
    const int half = lane >> 5;
    float4 lw[8];
    #pragma unroll
    for (int m = 0; m < 8; ++m) {
        lw[m] = *(const float4*)&lm_w[vv * HID + half * 32 + 4 * m];
        pin4(lw[m]);
    }
    const float lb = (half == 0 && vmod < VOCAB) ? lm_b[lane] : 0.0f;

    float h = start[lane];                    // h_{-1}
    float* outb = out + (size_t)b * TLEN * VOCAB;
    float xp = table[xrow[wave][0]][lane];    // xp for t=0

    for (int t = 0; t < TLEN; ++t) {
        // Prefetch next xp (uniform token -> per-lane table row, conflict-free).
        const int   tok_n = xrow[wave][(t + 1) & (TLEN - 1)];
        const float xp_n  = table[tok_n][lane];

        // Publish h_{t-1}; wave-private buffer, compiler inserts lgkmcnt.
        hbuf[wave][lane] = h;
        const float4* hb = (const float4*)&hbuf[wave][0];         // uniform bcast
        const float4* hh = (const float4*)&hbuf[wave][half * 32]; // 2-addr bcast

        // 4 recurrence chains (depth 16) + 2 logit chains (depth 16).
        float a0 = xp, a1 = 0.0f, a2 = 0.0f, a3 = 0.0f;
        float l0 = lb, l1 = 0.0f;
        #pragma unroll
        for (int k = 0; k < 4; ++k) {
            const float4 h0 = hb[4 * k + 0];
            const float4 h1 = hb[4 * k + 1];
            const float4 h2 = hb[4 * k + 2];
            const float4 h3 = hb[4 * k + 3];
            fma4(a0, wh[4 * k + 0], h0);
            fma4(a1, wh[4 * k + 1], h1);
            fma4(a2, wh[4 * k + 2], h2);
            fma4(a3, wh[4 * k + 3], h3);
            const float4 g0 = hh[2 * k + 0];
            const float4 g1 = hh[2 * k + 1];
            fma4(l0, lw[2 * k + 0], g0);
            fma4(l1, lw[2 * k + 1], g1);
        }

        float lg = l0 + l1;
        lg += __shfl_xor(lg, 32, 64);
        if (t > 0 && lane < VOCAB)
            outb[(size_t)(t - 1) * VOCAB + lane] = lg;

        h  = fast_tanh((a0 + a1) + (a2 + a3));   // h_t
        xp = xp_n;
    }

    // Final logits for t = T-1 from h_{T-1}.
    {
        hbuf[wave][lane] = h;
        const float4* hh = (const float4*)&hbuf[wave][half * 32];
        float l0 = lb, l1 = 0.0f;
        #pragma unroll
        for (int k = 0; k < 4; ++k) {
            const float4 g0 = hh[2 * k + 0];
            const float4 g1 = hh[2 * k + 1];
            fma4(l0, lw[2 * k + 0], g0);
            fma4(l1, lw[2 * k + 1], g1);
        }
        float lg = l0 + l1;
        lg += __shfl_xor(lg, 32, 64);
        if (lane < VOCAB)
            outb[(size_t)(TLEN - 1) * VOCAB + lane] = lg;
    }
}

extern "C" void kernel_launch(void* const* d_in, const int* in_sizes, int n_in,
                              void* d_out, int out_size, void* d_ws, size_t ws_size,
                              hipStream_t stream) {
    const int*   X     = (const int*)  d_in[0];
    const float* emb_w = (const float*)d_in[1];
    const float* start = (const float*)d_in[2];
    const float* rnn_w = (const float*)d_in[3];
    const float* rnn_b = (const float*)d_in[4];
    const float* lm_w  = (const float*)d_in[5];
    const float* lm_b  = (const float*)d_in[6];
    float*       out   = (float*)d_out;

    dim3 grid(BATCH / WPB);
    dim3 block(256);
    rnn_fused<<<grid, block, 0, stream>>>(X, emb_w, start, rnn_w, rnn_b,
                                          lm_w, lm_b, out);
}

// Round 9
// 373.539 us; speedup vs baseline: 1.2335x; 1.2335x over previous
//
#include <hip/hip_runtime.h>

#define VOCAB 27
#define EMB   32
#define HID   64
#define BATCH 4096
#define TLEN  256
#define ROWS  16          // batch rows per wave (one 16-row MFMA group)
#define WROW  96          // rnn_w row stride in floats
#define TPAD  65          // xp table row stride (floats, bank-staggered)
#define HPAD  68          // H buffer row stride (floats, 16B-aligned + bank-staggered)

typedef __attribute__((ext_vector_type(8))) short  bf16x8;  // 8 bf16 in 4 VGPRs
typedef __attribute__((ext_vector_type(4))) float  f32x4;   // mfma accumulator

// tanh(x) = 1 - 2/(exp2(2*log2e*x)+1) -- inline VALU, no libcall.
__device__ __forceinline__ float fast_tanh(float x) {
    float t = __builtin_amdgcn_exp2f(x * 2.885390081777927f);
    float r = __builtin_amdgcn_rcpf(t + 1.0f);
    return fmaf(-2.0f, r, 1.0f);
}
// fp32 -> bf16 bits, round-half-up (bias 2^-25, irrelevant; lo-part captures residual)
__device__ __forceinline__ unsigned bfbits(float f) {
    return (__float_as_uint(f) + 0x8000u) >> 16;
}
__device__ __forceinline__ unsigned bfpack(float e0, float e1) {
    return bfbits(e0) | (bfbits(e1) << 16);
}

union Frag { unsigned u[4]; bf16x8 v; };

__global__ __launch_bounds__(64, 1) void rnn_mfma(
    const int*   __restrict__ X,      // (B,T)
    const float* __restrict__ emb_w,  // (27,32)
    const float* __restrict__ start,  // (1,64)
    const float* __restrict__ rnn_w,  // (64,96) [:, :32]=Wx [:, 32:]=Wh
    const float* __restrict__ rnn_b,  // (64)
    const float* __restrict__ lm_w,   // (27,64)
    const float* __restrict__ lm_b,   // (27)
    float*       __restrict__ out)    // (B,T,27)
{
    __shared__ float         tabf[VOCAB * TPAD];   // xp table: rnn_b + Wx.emb[v]
    __shared__ float         Hbuf[ROWS * HPAD];    // h (fp32), C-layout -> A-layout relay
    __shared__ unsigned char tok8[ROWS * TLEN];    // token ids, 8-bit

    const int tid = threadIdx.x;   // one wave per block
    const int cc  = tid & 15;      // MFMA n / A-row index
    const int q   = tid >> 4;      // MFMA k-group / C-row group
    const int b0  = blockIdx.x * ROWS;

    // ---------------- prologue ----------------
    // xp lookup table (collapses embedding gather + xproj einsum)
    for (int f = tid; f < VOCAB * HID; f += 64) {
        const int v = f >> 6, i = f & 63;
        float s = rnn_b[i];
        #pragma unroll
        for (int e = 0; e < EMB; ++e)
            s = fmaf(rnn_w[i * WROW + e], emb_w[v * EMB + e], s);
        tabf[v * TPAD + i] = s;
    }
    // stage this group's tokens
    for (int idx = tid; idx < ROWS * TLEN; idx += 64) {
        const int r = idx >> 8, t = idx & 255;
        tok8[r * TLEN + t] = (unsigned char)X[(size_t)(b0 + r) * TLEN + t];
    }
    // h_{-1} = start, broadcast to all 16 rows
    for (int idx = tid; idx < ROWS * HID; idx += 64) {
        const int r = idx >> 6, j = idx & 63;
        Hbuf[r * HPAD + j] = start[j];
    }

    // Wh^T B-fragments, split hi/lo bf16 (lane: n = it*16+cc, k = q*8+e+kc*32).
    Frag whh[4][2], whl[4][2];
    #pragma unroll
    for (int it = 0; it < 4; ++it)
      #pragma unroll
      for (int kc = 0; kc < 2; ++kc) {
        const float* wr = &rnn_w[(it * 16 + cc) * WROW + EMB + q * 8 + kc * 32];
        #pragma unroll
        for (int p = 0; p < 4; ++p) {
            const float w0 = wr[2 * p], w1 = wr[2 * p + 1];
            const unsigned h0 = bfbits(w0), h1 = bfbits(w1);
            whh[it][kc].u[p] = h0 | (h1 << 16);
            whl[it][kc].u[p] = bfpack(w0 - __uint_as_float(h0 << 16),
                                      w1 - __uint_as_float(h1 << 16));
        }
      }
    // lm_w^T B-fragments, split hi/lo (lane: v = nt*16+cc, k = q*8+e+kc*32).
    Frag lwh[2][2], lwl[2][2];
    #pragma unroll
    for (int nt = 0; nt < 2; ++nt)
      #pragma unroll
      for (int kc = 0; kc < 2; ++kc) {
        const int  v  = nt * 16 + cc;
        const bool ok = v < VOCAB;
        const float* wr = &lm_w[(ok ? v : 0) * HID + q * 8 + kc * 32];
        #pragma unroll
        for (int p = 0; p < 4; ++p) {
            const float w0 = ok ? wr[2 * p] : 0.0f;
            const float w1 = ok ? wr[2 * p + 1] : 0.0f;
            const unsigned h0 = bfbits(w0), h1 = bfbits(w1);
            lwh[nt][kc].u[p] = h0 | (h1 << 16);
            lwl[nt][kc].u[p] = bfpack(w0 - __uint_as_float(h0 << 16),
                                      w1 - __uint_as_float(h1 << 16));
        }
      }
    const float lb0 = lm_b[cc];
    const float lb1 = (16 + cc < VOCAB) ? lm_b[16 + cc] : 0.0f;

    __syncthreads();   // single wave; cheap safety for LDS ordering

    // A-fragment (re)build from Hbuf: lane reads H[cc][q*8+e+kc*32], split hi/lo.
    Frag ah[2], al[2];
    auto build_frags = [&]() {
        #pragma unroll
        for (int kc = 0; kc < 2; ++kc) {
            const f32x4* hp = (const f32x4*)&Hbuf[cc * HPAD + q * 8 + kc * 32];
            const f32x4 h0 = hp[0], h1 = hp[1];
            const float e[8] = {h0[0], h0[1], h0[2], h0[3], h1[0], h1[1], h1[2], h1[3]};
            #pragma unroll
            for (int p = 0; p < 4; ++p) {
                const float x0 = e[2 * p], x1 = e[2 * p + 1];
                const unsigned hb0 = bfbits(x0), hb1 = bfbits(x1);
                ah[kc].u[p] = hb0 | (hb1 << 16);
                al[kc].u[p] = bfpack(x0 - __uint_as_float(hb0 << 16),
                                     x1 - __uint_as_float(hb1 << 16));
            }
        }
    };
    build_frags();

    // ---------------- main loop ----------------
    for (int t = 0; t < TLEN; ++t) {
        // C-init = xp (token-indexed table rows); lane's 4 rows are b=4q+r.
        int tk[4];
        #pragma unroll
        for (int r = 0; r < 4; ++r)
            tk[r] = tok8[(4 * q + r) * TLEN + t];
        f32x4 acc[4];
        #pragma unroll
        for (int it = 0; it < 4; ++it)
            #pragma unroll
            for (int r = 0; r < 4; ++r)
                acc[it][r] = tabf[tk[r] * TPAD + it * 16 + cc];

        // pre_t = H_{t-1} . Wh^T + xp   (hi*hi + lo*hi + hi*lo; lo*lo ~2^-17, dropped)
        #pragma unroll
        for (int it = 0; it < 4; ++it)
            #pragma unroll
            for (int kc = 0; kc < 2; ++kc) {
                acc[it] = __builtin_amdgcn_mfma_f32_16x16x32_bf16(ah[kc].v, whh[it][kc].v, acc[it], 0, 0, 0);
                acc[it] = __builtin_amdgcn_mfma_f32_16x16x32_bf16(al[kc].v, whh[it][kc].v, acc[it], 0, 0, 0);
                acc[it] = __builtin_amdgcn_mfma_f32_16x16x32_bf16(ah[kc].v, whl[it][kc].v, acc[it], 0, 0, 0);
            }

        // h_t = tanh(pre) -> Hbuf (C-layout scatter; 2-way-max bank alias at HPAD=68)
        #pragma unroll
        for (int it = 0; it < 4; ++it)
            #pragma unroll
            for (int r = 0; r < 4; ++r)
                Hbuf[(4 * q + r) * HPAD + it * 16 + cc] = fast_tanh(acc[it][r]);

        // redistribute h_t into A-fragments (the per-step transpose, via LDS)
        build_frags();

        // logits_t = h_t . lm_w^T + lm_b
        f32x4 lc0 = {lb0, lb0, lb0, lb0};
        f32x4 lc1 = {lb1, lb1, lb1, lb1};
        #pragma unroll
        for (int kc = 0; kc < 2; ++kc) {
            lc0 = __builtin_amdgcn_mfma_f32_16x16x32_bf16(ah[kc].v, lwh[0][kc].v, lc0, 0, 0, 0);
            lc0 = __builtin_amdgcn_mfma_f32_16x16x32_bf16(al[kc].v, lwh[0][kc].v, lc0, 0, 0, 0);
            lc0 = __builtin_amdgcn_mfma_f32_16x16x32_bf16(ah[kc].v, lwl[0][kc].v, lc0, 0, 0, 0);
            lc1 = __builtin_amdgcn_mfma_f32_16x16x32_bf16(ah[kc].v, lwh[1][kc].v, lc1, 0, 0, 0);
            lc1 = __builtin_amdgcn_mfma_f32_16x16x32_bf16(al[kc].v, lwh[1][kc].v, lc1, 0, 0, 0);
            lc1 = __builtin_amdgcn_mfma_f32_16x16x32_bf16(ah[kc].v, lwl[1][kc].v, lc1, 0, 0, 0);
        }

        // store: C-layout (row b=4q+r, col v=nt*16+cc), guard v<27
        const size_t rowbase = ((size_t)(b0 + 4 * q) * TLEN + t) * VOCAB;
        #pragma unroll
        for (int r = 0; r < 4; ++r) {
            out[rowbase + (size_t)r * (TLEN * VOCAB) + cc] = lc0[r];
            if (cc < VOCAB - 16)
                out[rowbase + (size_t)r * (TLEN * VOCAB) + 16 + cc] = lc1[r];
        }
    }
}

extern "C" void kernel_launch(void* const* d_in, const int* in_sizes, int n_in,
                              void* d_out, int out_size, void* d_ws, size_t ws_size,
                              hipStream_t stream) {
    const int*   X     = (const int*)  d_in[0];
    const float* emb_w = (const float*)d_in[1];
    const float* start = (const float*)d_in[2];
    const float* rnn_w = (const float*)d_in[3];
    const float* rnn_b = (const float*)d_in[4];
    const float* lm_w  = (const float*)d_in[5];
    const float* lm_b  = (const float*)d_in[6];
    float*       out   = (float*)d_out;

    dim3 grid(BATCH / ROWS);   // 256 blocks, one 64-thread wave each
    dim3 block(64);
    rnn_mfma<<<grid, block, 0, stream>>>(X, emb_w, start, rnn_w, rnn_b,
                                         lm_w, lm_b, out);
}

// Round 13
// 244.287 us; speedup vs baseline: 1.8861x; 1.5291x over previous
//
#include <hip/hip_runtime.h>

#define VOCAB 27
#define EMB   32
#define HID   64
#define BATCH 4096
#define TLEN  256
#define ROWS  16          // batch rows per block (one MFMA M-tile)
#define WROW  96          // rnn_w row stride in floats
#define TPAD  65          // xp table row stride (floats)
#define HROW  72          // h relay row stride in ushort (144 B, 16B-aligned)

typedef __attribute__((ext_vector_type(8))) short bf16x8;
typedef __attribute__((ext_vector_type(4))) float f32x4;

// tanh(x) = 1 - 2/(exp2(2*log2e*x)+1) -- inline VALU, no libcall.
__device__ __forceinline__ float fast_tanh(float x) {
    float t = __builtin_amdgcn_exp2f(x * 2.885390081777927f);
    float r = __builtin_amdgcn_rcpf(t + 1.0f);
    return fmaf(-2.0f, r, 1.0f);
}
// fp32 -> bf16 bits, round-half-up; residual captured by lo part.
__device__ __forceinline__ unsigned bfbits(float f) {
    return (__float_as_uint(f) + 0x8000u) >> 16;
}

union Frag { unsigned u[4]; bf16x8 v; };

__device__ __forceinline__ f32x4 mfma16(bf16x8 a, bf16x8 b, f32x4 c) {
    return __builtin_amdgcn_mfma_f32_16x16x32_bf16(a, b, c, 0, 0, 0);
}

__global__ __launch_bounds__(256, 1) void rnn_mfma4(
    const int*   __restrict__ X,      // (B,T)
    const float* __restrict__ emb_w,  // (27,32)
    const float* __restrict__ start,  // (1,64)
    const float* __restrict__ rnn_w,  // (64,96) [:, :32]=Wx [:, 32:]=Wh
    const float* __restrict__ rnn_b,  // (64)
    const float* __restrict__ lm_w,   // (27,64)
    const float* __restrict__ lm_b,   // (27)
    float*       __restrict__ out)    // (B,T,27)
{
    __shared__ __align__(16) float          tabf[VOCAB * TPAD];
    __shared__ __align__(16) unsigned short Hhi[2][ROWS * HROW];  // h hi bf16
    __shared__ __align__(16) unsigned short Hlo[2][ROWS * HROW];  // h lo bf16
    __shared__               unsigned char  tok8[ROWS * TLEN];

    const int tid  = threadIdx.x;
    const int lane = tid & 63;
    const int w    = tid >> 6;       // wave id = out-hidden tile (it)
    const int cc   = lane & 15;
    const int q    = lane >> 4;
    const int b0   = blockIdx.x * ROWS;
    const int colh = w * 16 + cc;    // this wave's out-hidden column

    // ---------------- prologue ----------------
    // xp lookup table: rnn_b + Wx . emb_w[v]  (collapses embedding + xproj)
    for (int f = tid; f < VOCAB * HID; f += 256) {
        const int v = f >> 6, i = f & 63;
        float s = rnn_b[i];
        #pragma unroll
        for (int e = 0; e < EMB; ++e)
            s = fmaf(rnn_w[i * WROW + e], emb_w[v * EMB + e], s);
        tabf[v * TPAD + i] = s;
    }
    // token staging (8-bit)
    for (int idx = tid; idx < ROWS * TLEN; idx += 256) {
        const int r = idx >> 8, t = idx & 255;
        tok8[idx] = (unsigned char)X[(size_t)(b0 + r) * TLEN + t];
    }
    // h_{-1} = start, pre-split bf16 hi/lo into buffer 1
    for (int idx = tid; idx < ROWS * HID; idx += 256) {
        const int r = idx >> 6, j = idx & 63;
        const float s = start[j];
        const unsigned hb = bfbits(s);
        Hhi[1][r * HROW + j] = (unsigned short)hb;
        Hlo[1][r * HROW + j] = (unsigned short)bfbits(s - __uint_as_float(hb << 16));
    }

    // Wh^T B-fragments for this wave's tile, hi/lo split (proven layout, R9).
    Frag whh[2], whl[2];
    #pragma unroll
    for (int kc = 0; kc < 2; ++kc) {
        const float* wr = &rnn_w[colh * WROW + EMB + q * 8 + kc * 32];
        #pragma unroll
        for (int p = 0; p < 4; ++p) {
            const float w0 = wr[2 * p], w1 = wr[2 * p + 1];
            const unsigned h0 = bfbits(w0), h1 = bfbits(w1);
            whh[kc].u[p] = h0 | (h1 << 16);
            whl[kc].u[p] = bfbits(w0 - __uint_as_float(h0 << 16)) |
                           (bfbits(w1 - __uint_as_float(h1 << 16)) << 16);
        }
    }
    // lm_w^T B-fragments on waves 2,3 (vocab tiles 0-15 / 16-26).
    Frag lwh[2], lwl[2];
    float lb = 0.0f;
    if (w >= 2) {
        const int  nt = w - 2;
        const int  v  = nt * 16 + cc;
        const bool ok = v < VOCAB;
        #pragma unroll
        for (int kc = 0; kc < 2; ++kc) {
            const float* wr = &lm_w[(ok ? v : 0) * HID + q * 8 + kc * 32];
            #pragma unroll
            for (int p = 0; p < 4; ++p) {
                const float w0 = ok ? wr[2 * p] : 0.0f;
                const float w1 = ok ? wr[2 * p + 1] : 0.0f;
                const unsigned h0 = bfbits(w0), h1 = bfbits(w1);
                lwh[kc].u[p] = h0 | (h1 << 16);
                lwl[kc].u[p] = bfbits(w0 - __uint_as_float(h0 << 16)) |
                               (bfbits(w1 - __uint_as_float(h1 << 16)) << 16);
            }
        }
        lb = ok ? lm_b[v] : 0.0f;
    }

    __syncthreads();

    // initial A-frags (h_{-1}) from buffer 1: direct b128 reads of packed bf16
    Frag ah[2], al[2];
    #pragma unroll
    for (int kc = 0; kc < 2; ++kc) {
        ah[kc].v = *(const bf16x8*)&Hhi[1][cc * HROW + q * 8 + kc * 32];
        al[kc].v = *(const bf16x8*)&Hlo[1][cc * HROW + q * 8 + kc * 32];
    }
    // xp(0) prefetch
    int   tkn[4];
    float xq[4];
    #pragma unroll
    for (int r = 0; r < 4; ++r) {
        tkn[r] = tok8[(4 * q + r) * TLEN];
        xq[r]  = tabf[tkn[r] * TPAD + colh];
    }

    // ---------------- main loop ----------------
    for (int t = 0; t < TLEN; ++t) {
        // issue next-step token reads early (hide under MFMAs)
        const int tn = (t + 1) & (TLEN - 1);
        #pragma unroll
        for (int r = 0; r < 4; ++r)
            tkn[r] = tok8[(4 * q + r) * TLEN + tn];

        // rec: 3 independent accumulators, depth-2 MFMA chains
        f32x4 a0 = {xq[0], xq[1], xq[2], xq[3]};
        f32x4 a1 = {0.0f, 0.0f, 0.0f, 0.0f};
        f32x4 a2 = {0.0f, 0.0f, 0.0f, 0.0f};
        a0 = mfma16(ah[0].v, whh[0].v, a0); a0 = mfma16(ah[1].v, whh[1].v, a0);
        a1 = mfma16(al[0].v, whh[0].v, a1); a1 = mfma16(al[1].v, whh[1].v, a1);
        a2 = mfma16(ah[0].v, whl[0].v, a2); a2 = mfma16(ah[1].v, whl[1].v, a2);

        // h_t slice: tanh, split hi/lo, write packed bf16 (consumer split-free)
        const int buf = t & 1;
        #pragma unroll
        for (int r = 0; r < 4; ++r) {
            const float hv = fast_tanh((a0[r] + a1[r]) + a2[r]);
            const unsigned hb = bfbits(hv);
            Hhi[buf][(4 * q + r) * HROW + colh] = (unsigned short)hb;
            Hlo[buf][(4 * q + r) * HROW + colh] =
                (unsigned short)bfbits(hv - __uint_as_float(hb << 16));
        }

        __syncthreads();

        // read full h_t A-frags (b128, packed bf16 — no split VALU)
        #pragma unroll
        for (int kc = 0; kc < 2; ++kc) {
            ah[kc].v = *(const bf16x8*)&Hhi[buf][cc * HROW + q * 8 + kc * 32];
            al[kc].v = *(const bf16x8*)&Hlo[buf][cc * HROW + q * 8 + kc * 32];
        }
        // xp(t+1) gather (tokens already in regs; overlaps frag-read latency)
        #pragma unroll
        for (int r = 0; r < 4; ++r)
            xq[r] = tabf[tkn[r] * TPAD + colh];

        // logits_t on waves 2,3 (hidden under waves 0,1's next rec)
        if (w >= 2) {
            f32x4 g0 = {lb, lb, lb, lb};
            f32x4 g1 = {0.0f, 0.0f, 0.0f, 0.0f};
            f32x4 g2 = {0.0f, 0.0f, 0.0f, 0.0f};
            g0 = mfma16(ah[0].v, lwh[0].v, g0); g0 = mfma16(ah[1].v, lwh[1].v, g0);
            g1 = mfma16(al[0].v, lwh[0].v, g1); g1 = mfma16(al[1].v, lwh[1].v, g1);
            g2 = mfma16(ah[0].v, lwl[0].v, g2); g2 = mfma16(ah[1].v, lwl[1].v, g2);
            const int col = (w - 2) * 16 + cc;
            if (col < VOCAB) {
                const size_t base =
                    ((size_t)(b0 + 4 * q) * TLEN + t) * VOCAB + col;
                #pragma unroll
                for (int r = 0; r < 4; ++r)
                    out[base + (size_t)r * (TLEN * VOCAB)] = (g0[r] + g1[r]) + g2[r];
            }
        }
    }
}

extern "C" void kernel_launch(void* const* d_in, const int* in_sizes, int n_in,
                              void* d_out, int out_size, void* d_ws, size_t ws_size,
                              hipStream_t stream) {
    const int*   X     = (const int*)  d_in[0];
    const float* emb_w = (const float*)d_in[1];
    const float* start = (const float*)d_in[2];
    const float* rnn_w = (const float*)d_in[3];
    const float* rnn_b = (const float*)d_in[4];
    const float* lm_w  = (const float*)d_in[5];
    const float* lm_b  = (const float*)d_in[6];
    float*       out   = (float*)d_out;

    dim3 grid(BATCH / ROWS);   // 256 blocks: one 16-row group, 4 waves each
    dim3 block(256);
    rnn_mfma4<<<grid, block, 0, stream>>>(X, emb_w, start, rnn_w, rnn_b,
                                          lm_w, lm_b, out);
}